// Round 1
// baseline (2641.396 us; speedup 1.0000x reference)
//
#include <hip/hip_runtime.h>

#define EPS 1e-5f

// fast accurate-enough tanh: 1 v_exp + 1 v_rcp, abs err ~1e-7, no overflow
__device__ __forceinline__ float tanh_fast(float x) {
  float ax = fabsf(x);
  float e  = __expf(-2.0f * ax);
  float r  = (1.0f - e) * __builtin_amdgcn_rcpf(1.0f + e);
  return copysignf(r, x);
}

// ---------------------------------------------------------------------------
// Kernel A: h0 = tanh(groupnorm(x @ W_in + b_in) * gamma1 + beta1)
// block = 256 threads = 64 rows x 4 K-quads (each quad handles 196 of 784 k's)
// grid = 65536/64 = 1024 blocks (4 blocks/CU, 4 waves/SIMD)
// No LDS: quad partial sums reduced with __shfl_xor (quad lanes are adjacent).
// ---------------------------------------------------------------------------
__global__ __launch_bounds__(256, 4) void kA(
    const float* __restrict__ x, const float* __restrict__ Win,
    const float* __restrict__ bin, const float* __restrict__ g1,
    const float* __restrict__ be1, float* __restrict__ h0) {
  const int tid = threadIdx.x;
  const int r = tid >> 2, q = tid & 3;            // row-in-block, k-quad
  const size_t row = (size_t)blockIdx.x * 64 + r;
  const float4* __restrict__ x4 = (const float4*)x + row * (784 / 4) + q * 49;
  const float4* __restrict__ W4 = (const float4*)Win;   // [784][16] float4

  float acc[64];
#pragma unroll
  for (int j = 0; j < 64; ++j) acc[j] = 0.f;

  const int kbase = q * 196;
#pragma unroll 2
  for (int i4 = 0; i4 < 49; ++i4) {
    float4 xv = x4[i4];
    const float4* __restrict__ wrow = W4 + (size_t)(kbase + i4 * 4) * 16;
#pragma unroll
    for (int i = 0; i < 4; ++i) {
      float xs = (i == 0) ? xv.x : (i == 1) ? xv.y : (i == 2) ? xv.z : xv.w;
      const float4* __restrict__ wr = wrow + i * 16;
#pragma unroll
      for (int j4 = 0; j4 < 16; ++j4) {
        float4 w = wr[j4];
        acc[4 * j4 + 0] = fmaf(xs, w.x, acc[4 * j4 + 0]);
        acc[4 * j4 + 1] = fmaf(xs, w.y, acc[4 * j4 + 1]);
        acc[4 * j4 + 2] = fmaf(xs, w.z, acc[4 * j4 + 2]);
        acc[4 * j4 + 3] = fmaf(xs, w.w, acc[4 * j4 + 3]);
      }
    }
  }

  // reduce across the 4 quad lanes (masks 1,2 stay inside the quad)
#pragma unroll
  for (int j = 0; j < 64; ++j) {
    acc[j] += __shfl_xor(acc[j], 1, 64);
    acc[j] += __shfl_xor(acc[j], 2, 64);
  }

  // each lane keeps its 16 channels (2 groupnorm groups). q is runtime ->
  // use an exec-masked static extract (rule #20: no runtime reg indexing).
  float v[16];
  if (q == 0) {
#pragma unroll
    for (int j = 0; j < 16; ++j) v[j] = acc[j];
  } else if (q == 1) {
#pragma unroll
    for (int j = 0; j < 16; ++j) v[j] = acc[16 + j];
  } else if (q == 2) {
#pragma unroll
    for (int j = 0; j < 16; ++j) v[j] = acc[32 + j];
  } else {
#pragma unroll
    for (int j = 0; j < 16; ++j) v[j] = acc[48 + j];
  }
  const int c0 = q * 16;
#pragma unroll
  for (int j = 0; j < 16; ++j) v[j] += bin[c0 + j];

  float o[16];
#pragma unroll
  for (int g = 0; g < 2; ++g) {
    float mu = 0.f;
#pragma unroll
    for (int i = 0; i < 8; ++i) mu += v[g * 8 + i];
    mu *= 0.125f;
    float var = 0.f;
#pragma unroll
    for (int i = 0; i < 8; ++i) { float d = v[g * 8 + i] - mu; var = fmaf(d, d, var); }
    var *= 0.125f;
    float rs = rsqrtf(var + EPS);
#pragma unroll
    for (int i = 0; i < 8; ++i) {
      float y = (v[g * 8 + i] - mu) * rs * g1[c0 + g * 8 + i] + be1[c0 + g * 8 + i];
      o[g * 8 + i] = tanh_fast(y);
    }
  }

  float4* dst = (float4*)(h0 + row * 64 + c0);
#pragma unroll
  for (int i = 0; i < 4; ++i)
    dst[i] = make_float4(o[4 * i], o[4 * i + 1], o[4 * i + 2], o[4 * i + 3]);
}

// ---------------------------------------------------------------------------
// Kernel B: RK4 x num_steps, then groupnorm2 -> W_out -> log_softmax.
// block = 256 threads = 128 rows x 2 halves (32 channels each); grid = 512.
// Weights in LDS (broadcast float4 reads). Matvec INPUT vector in LDS
// (u[128][65], +1 pad -> conflict-free) so the k-loop stays dynamic
// (small icache body, no scratch). Row halves are lane pairs (tid&1) in the
// same wave: lockstep + lgkmcnt(0) makes the LDS RAW safe without barriers.
// LDS total ~69.7 KB -> 2 blocks/CU, 2 waves/SIMD.
// ---------------------------------------------------------------------------
__global__ __launch_bounds__(256, 2) void kB(
    const float* __restrict__ h0,
    const float* __restrict__ W1, const float* __restrict__ b1,
    const float* __restrict__ W2, const float* __restrict__ b2,
    const float* __restrict__ g2, const float* __restrict__ be2,
    const float* __restrict__ Wout, const float* __restrict__ bout,
    const int* __restrict__ nsp, float* __restrict__ out) {
  __shared__ __align__(16) float w1s[4096];
  __shared__ __align__(16) float w2s[4096];
  __shared__ float b1s[64], b2s[64], g2s[64], be2s[64], wos[640], bos[10];
  __shared__ float u[128 * 65];

  const int tid = threadIdx.x;
  {
    float4* d1 = (float4*)w1s; const float4* s1 = (const float4*)W1;
    float4* d2 = (float4*)w2s; const float4* s2 = (const float4*)W2;
#pragma unroll 1
    for (int i = tid; i < 1024; i += 256) { d1[i] = s1[i]; d2[i] = s2[i]; }
    if (tid < 64) {
      b1s[tid] = b1[tid]; b2s[tid] = b2[tid];
      g2s[tid] = g2[tid]; be2s[tid] = be2[tid];
    }
#pragma unroll 1
    for (int i = tid; i < 640; i += 256) wos[i] = Wout[i];
    if (tid < 10) bos[tid] = bout[tid];
  }
  __syncthreads();

  const int r = tid >> 1, hf = tid & 1;
  const int ch0 = hf * 32;
  const size_t row = (size_t)blockIdx.x * 128 + r;
  float* __restrict__ ur = u + r * 65;

  float h[32];
  const float4* hsrc = (const float4*)(h0 + row * 64 + ch0);
#pragma unroll
  for (int i = 0; i < 8; ++i) {
    float4 t4 = hsrc[i];
    h[4 * i + 0] = t4.x; h[4 * i + 1] = t4.y;
    h[4 * i + 2] = t4.z; h[4 * i + 3] = t4.w;
  }

  const int ns = *nsp;                      // works for int32 or int64-LE
  const float dt  = 1.0f / (float)ns;
  const float dt6 = dt * (1.0f / 6.0f);
  const float dt3 = dt * (1.0f / 3.0f);
  const float dth = dt * 0.5f;

  float s[32], kv[32];

#pragma unroll 1
  for (int step = 0; step < ns; ++step) {
    // arg <- h ; s <- h
#pragma unroll
    for (int j = 0; j < 32; ++j) { ur[ch0 + j] = h[j]; s[j] = h[j]; }
    __asm__ volatile("s_waitcnt lgkmcnt(0)" ::: "memory");

#pragma unroll 1
    for (int e = 0; e < 4; ++e) {
      // ---- f(arg): kv = W2^T tanh(W1^T arg + b1) + b2, arg in ur[0..63] ----
#pragma unroll
      for (int j = 0; j < 32; ++j) kv[j] = b1s[ch0 + j];
#pragma unroll 4
      for (int k = 0; k < 64; ++k) {
        float in = ur[k];
        const float4* wr = (const float4*)(w1s + k * 64 + ch0);
#pragma unroll
        for (int j4 = 0; j4 < 8; ++j4) {
          float4 w = wr[j4];
          kv[4 * j4 + 0] = fmaf(in, w.x, kv[4 * j4 + 0]);
          kv[4 * j4 + 1] = fmaf(in, w.y, kv[4 * j4 + 1]);
          kv[4 * j4 + 2] = fmaf(in, w.z, kv[4 * j4 + 2]);
          kv[4 * j4 + 3] = fmaf(in, w.w, kv[4 * j4 + 3]);
        }
      }
#pragma unroll
      for (int j = 0; j < 32; ++j) ur[ch0 + j] = tanh_fast(kv[j]);
      __asm__ volatile("s_waitcnt lgkmcnt(0)" ::: "memory");
#pragma unroll
      for (int j = 0; j < 32; ++j) kv[j] = b2s[ch0 + j];
#pragma unroll 4
      for (int k = 0; k < 64; ++k) {
        float in = ur[k];
        const float4* wr = (const float4*)(w2s + k * 64 + ch0);
#pragma unroll
        for (int j4 = 0; j4 < 8; ++j4) {
          float4 w = wr[j4];
          kv[4 * j4 + 0] = fmaf(in, w.x, kv[4 * j4 + 0]);
          kv[4 * j4 + 1] = fmaf(in, w.y, kv[4 * j4 + 1]);
          kv[4 * j4 + 2] = fmaf(in, w.z, kv[4 * j4 + 2]);
          kv[4 * j4 + 3] = fmaf(in, w.w, kv[4 * j4 + 3]);
        }
      }
      // ---- RK4 update ----
      if (e < 3) {
        float cs = (e == 0) ? dt6 : dt3;
        float ca = (e == 2) ? dt : dth;
#pragma unroll
        for (int j = 0; j < 32; ++j) {
          s[j] = fmaf(cs, kv[j], s[j]);
          ur[ch0 + j] = fmaf(ca, kv[j], h[j]);   // next arg
        }
        __asm__ volatile("s_waitcnt lgkmcnt(0)" ::: "memory");
      } else {
#pragma unroll
        for (int j = 0; j < 32; ++j) h[j] = fmaf(dt6, kv[j], s[j]);
      }
    }
  }

  // ---- groupnorm2 (4 groups of 8 within my 32 channels) ----
  float g[32];
#pragma unroll
  for (int grp = 0; grp < 4; ++grp) {
    float mu = 0.f;
#pragma unroll
    for (int i = 0; i < 8; ++i) mu += h[grp * 8 + i];
    mu *= 0.125f;
    float var = 0.f;
#pragma unroll
    for (int i = 0; i < 8; ++i) { float d = h[grp * 8 + i] - mu; var = fmaf(d, d, var); }
    var *= 0.125f;
    float rs = rsqrtf(var + EPS);
#pragma unroll
    for (int i = 0; i < 8; ++i) {
      int c = grp * 8 + i;
      g[c] = (h[c] - mu) * rs * g2s[ch0 + c] + be2s[ch0 + c];
    }
  }

  // ---- logits (partial over my 32 k's) + pair reduce + log_softmax ----
  float lg[10];
#pragma unroll
  for (int c = 0; c < 10; ++c) lg[c] = 0.f;
#pragma unroll
  for (int j = 0; j < 32; ++j) {
    float gv = g[j];
    const float* wr = wos + (ch0 + j) * 10;
#pragma unroll
    for (int c = 0; c < 10; ++c) lg[c] = fmaf(gv, wr[c], lg[c]);
  }
#pragma unroll
  for (int c = 0; c < 10; ++c) lg[c] = lg[c] + __shfl_xor(lg[c], 1, 64) + bos[c];

  float m = lg[0];
#pragma unroll
  for (int c = 1; c < 10; ++c) m = fmaxf(m, lg[c]);
  float sum = 0.f;
#pragma unroll
  for (int c = 0; c < 10; ++c) sum += __expf(lg[c] - m);
  float lse = m + __logf(sum);

  if (hf == 0) {
    float* op = out + row * 10;
#pragma unroll
    for (int c = 0; c < 10; ++c) op[c] = lg[c] - lse;
  }
}

extern "C" void kernel_launch(void* const* d_in, const int* in_sizes, int n_in,
                              void* d_out, int out_size, void* d_ws, size_t ws_size,
                              hipStream_t stream) {
  const float* x    = (const float*)d_in[0];
  const float* Win  = (const float*)d_in[1];
  const float* bin  = (const float*)d_in[2];
  const float* g1   = (const float*)d_in[3];
  const float* be1  = (const float*)d_in[4];
  const float* W1   = (const float*)d_in[5];
  const float* b1   = (const float*)d_in[6];
  const float* W2   = (const float*)d_in[7];
  const float* b2   = (const float*)d_in[8];
  const float* g2   = (const float*)d_in[9];
  const float* be2  = (const float*)d_in[10];
  const float* Wout = (const float*)d_in[11];
  const float* bout = (const float*)d_in[12];
  const int*   nsp  = (const int*)d_in[13];
  float* out = (float*)d_out;
  float* h0  = (float*)d_ws;   // 65536*64*4 = 16.78 MB scratch

  kA<<<1024, 256, 0, stream>>>(x, Win, bin, g1, be1, h0);
  kB<<<512, 256, 0, stream>>>(h0, W1, b1, W2, b2, g2, be2, Wout, bout, nsp, out);
}